// Round 3
// baseline (614.842 us; speedup 1.0000x reference)
//
#include <hip/hip_runtime.h>
#include <hip/hip_bf16.h>

typedef __attribute__((ext_vector_type(4))) float f32x4;
typedef __attribute__((ext_vector_type(8))) short s16x8;
typedef __attribute__((ext_vector_type(4))) short s16x4;

#define LQS 520   // shared buf row stride (bf16 elems): 512 + 8 pad
#define FOS 260   // f32 out-staging row stride (floats)

// smem layout (bytes): one 64x520 bf16 buffer, multi-purpose:
//   phase A: cols 0..255 = x (bf16)
//   phase B: cols 0..255 = Q, cols 256..511 = K
//   phase C: cols 0..255 = attention output (bf16)
//   phase D: rows 0..48 as f32[49][260] = proj output staging
#define SZ_BUF    (64 * LQS * 2)          // 66560
#define OFF_LB    SZ_BUF
#define SZ_LB     (169 * 8 * 4)           // 5408
#define SMEM_BYTES (SZ_BUF + SZ_LB)       // 71968  -> 2 blocks/CU (LDS-wise)

__device__ __forceinline__ short f2bf(float f) {
    unsigned u = __builtin_bit_cast(unsigned, f);
    unsigned r = (u + 0x7FFFu + ((u >> 16) & 1u)) >> 16;
    return (short)r;
}

__device__ __forceinline__ unsigned pk2bf(float a, float b) {
    return (unsigned)(unsigned short)f2bf(a) | ((unsigned)(unsigned short)f2bf(b) << 16);
}

__device__ __forceinline__ int region_id(int wy, int wx, int ty, int tx) {
    int rr = wy * 7 + ty;
    int cc = wx * 7 + tx;
    int rh = (rr < 49) ? 0 : ((rr < 53) ? 1 : 2);
    int rw = (cc < 49) ? 0 : ((cc < 53) ? 1 : 2);
    return rh * 3 + rw;
}

// K0: convert weights fp32 -> bf16 into workspace
__global__ void wcvt_kernel(const float* __restrict__ qw, const float* __restrict__ pw,
                            short* __restrict__ wqkv, short* __restrict__ wproj) {
    int idx = blockIdx.x * blockDim.x + threadIdx.x;
    int stride = gridDim.x * blockDim.x;
    for (int i = idx; i < 65536; i += stride) {
        if (i < 49152) {
            const f32x4 v = *(const f32x4*)(qw + i * 4);
            s16x4 o = { f2bf(v.x), f2bf(v.y), f2bf(v.z), f2bf(v.w) };
            *(s16x4*)(wqkv + i * 4) = o;
        } else {
            int j = i - 49152;
            const f32x4 v = *(const f32x4*)(pw + j * 4);
            s16x4 o = { f2bf(v.x), f2bf(v.y), f2bf(v.z), f2bf(v.w) };
            *(s16x4*)(wproj + j * 4) = o;
        }
    }
}

__global__ __launch_bounds__(512, 4)
void swin_kernel(const float* __restrict__ x,
                 const float* __restrict__ qkv_bias,
                 const float* __restrict__ proj_bias,
                 const float* __restrict__ rpb,
                 const short* __restrict__ wqkv,
                 const short* __restrict__ wproj,
                 float* __restrict__ out) {
    __shared__ __align__(16) char smem[SMEM_BYTES];
    short* buf   = (short*)smem;
    float* lbias = (float*)(smem + OFF_LB);

    const int tid  = threadIdx.x;
    const int w    = tid >> 6;        // wave id == head id
    const int lane = tid & 63;
    const int il   = lane & 15;
    const int gl   = lane >> 4;

    const int b   = blockIdx.x >> 6;
    const int wid = blockIdx.x & 63;
    const int wy  = wid >> 3, wx = wid & 7;

    // ---------------- stage rpb table + window input (bf16, cols 0..255) ----
    for (int i = tid; i < 1352; i += 512) lbias[i] = rpb[i];
    for (int i = tid; i < 4096; i += 512) {  // 64 rows x 64 float4 chunks
        int t = i >> 6, c4 = (i & 63) << 2;
        s16x4 o;
        if (t < 49) {
            int ty = t / 7, tx = t % 7;
            int R = wy * 7 + ty + 3; if (R >= 56) R -= 56;
            int C = wx * 7 + tx + 3; if (C >= 56) C -= 56;
            const f32x4 v = *(const f32x4*)(x + (((b * 56 + R) * 56 + C) << 8) + c4);
            o = (s16x4){ f2bf(v.x), f2bf(v.y), f2bf(v.z), f2bf(v.w) };
        } else {
            o = (s16x4){ 0, 0, 0, 0 };
        }
        *(s16x4*)&buf[t * LQS + c4] = o;
    }
    __syncthreads();

    // ---------------- QKV GEMM, pass 1: V only (32 accs) ----------------
    unsigned pv[4][2][2];   // V head-w, packed bf16 pairs, lives through attention
    {
        f32x4 vacc[4][2];
        #pragma unroll
        for (int mi = 0; mi < 4; mi++)
            #pragma unroll
            for (int md = 0; md < 2; md++) vacc[mi][md] = (f32x4){0.f, 0.f, 0.f, 0.f};
        for (int k0 = 0; k0 < 256; k0 += 32) {
            s16x8 a[4];
            #pragma unroll
            for (int mi = 0; mi < 4; mi++)
                a[mi] = *(const s16x8*)&buf[(mi * 16 + il) * LQS + k0 + 8 * gl];
            #pragma unroll
            for (int md = 0; md < 2; md++) {
                s16x8 bfr = *(const s16x8*)(wqkv + (512 + 32 * w + 16 * md + il) * 256 + k0 + 8 * gl);
                #pragma unroll
                for (int mi = 0; mi < 4; mi++)
                    vacc[mi][md] = __builtin_amdgcn_mfma_f32_16x16x32_bf16(a[mi], bfr, vacc[mi][md], 0, 0, 0);
            }
        }
        #pragma unroll
        for (int md = 0; md < 2; md++) {
            float bv = qkv_bias[512 + 32 * w + 16 * md + il];
            #pragma unroll
            for (int mi = 0; mi < 4; mi++) {
                pv[mi][md][0] = pk2bf(vacc[mi][md][0] + bv, vacc[mi][md][1] + bv);
                pv[mi][md][1] = pk2bf(vacc[mi][md][2] + bv, vacc[mi][md][3] + bv);
            }
        }
    }

    // ---------------- QKV GEMM, pass 2: Q,K (64 accs) ----------------
    {
        int cb[4];
        cb[0] = 32 * w;       cb[1] = 32 * w + 16;
        cb[2] = 256 + 32 * w; cb[3] = 256 + 32 * w + 16;
        f32x4 acc[4][4];
        #pragma unroll
        for (int mi = 0; mi < 4; mi++)
            #pragma unroll
            for (int ni = 0; ni < 4; ni++) acc[mi][ni] = (f32x4){0.f, 0.f, 0.f, 0.f};
        for (int k0 = 0; k0 < 256; k0 += 32) {
            s16x8 a[4];
            #pragma unroll
            for (int mi = 0; mi < 4; mi++)
                a[mi] = *(const s16x8*)&buf[(mi * 16 + il) * LQS + k0 + 8 * gl];
            #pragma unroll
            for (int ni = 0; ni < 4; ni++) {
                s16x8 bfr = *(const s16x8*)(wqkv + (cb[ni] + il) * 256 + k0 + 8 * gl);
                #pragma unroll
                for (int mi = 0; mi < 4; mi++)
                    acc[mi][ni] = __builtin_amdgcn_mfma_f32_16x16x32_bf16(a[mi], bfr, acc[mi][ni], 0, 0, 0);
            }
        }
        __syncthreads();   // all x reads (both passes) done; buf -> Q,K
        #pragma unroll
        for (int ni = 0; ni < 4; ni++) {
            int col = cb[ni] + il;
            float bv = qkv_bias[col];
            float scl = (ni < 2) ? 0.17677669529663687f : 1.0f;
            #pragma unroll
            for (int mi = 0; mi < 4; mi++)
                #pragma unroll
                for (int r = 0; r < 4; r++)
                    buf[(mi * 16 + gl * 4 + r) * LQS + col] = f2bf((acc[mi][ni][r] + bv) * scl);
        }
    }
    __syncthreads();

    // ---------------- attention, head h = w ----------------
    const int h = w;
    f32x4 s[4][4];
    {
        s16x8 ak[4], bq[4];
        #pragma unroll
        for (int mi = 0; mi < 4; mi++)
            ak[mi] = *(const s16x8*)&buf[(mi * 16 + il) * LQS + 256 + 32 * h + 8 * gl];
        #pragma unroll
        for (int ni = 0; ni < 4; ni++)
            bq[ni] = *(const s16x8*)&buf[(ni * 16 + il) * LQS + 32 * h + 8 * gl];
        __syncthreads();   // all q/k frag reads done; buf free for attn output
        #pragma unroll
        for (int mi = 0; mi < 4; mi++)
            #pragma unroll
            for (int ni = 0; ni < 4; ni++)
                s[mi][ni] = __builtin_amdgcn_mfma_f32_16x16x32_bf16(ak[mi], bq[ni], (f32x4){0.f,0.f,0.f,0.f}, 0, 0, 0);
    }
    // scores layout: s[mi][ni][r] = score[ query i = ni*16+il ][ key j = mi*16+gl*4+r ]
    int yi[4], xi[4], cnti[4];
    #pragma unroll
    for (int ni = 0; ni < 4; ni++) {
        int i = ni * 16 + il; int ic = i > 48 ? 48 : i;
        yi[ni] = ic / 7; xi[ni] = ic % 7;
        cnti[ni] = region_id(wy, wx, yi[ni], xi[ni]);
    }
    float mx[4] = { -1e30f, -1e30f, -1e30f, -1e30f };
    #pragma unroll
    for (int mi = 0; mi < 4; mi++) {
        #pragma unroll
        for (int r = 0; r < 4; r++) {
            int j = mi * 16 + gl * 4 + r;
            bool jok = (j < 49);
            int jc = jok ? j : 48;
            int yj = jc / 7, xj = jc % 7;
            int cj = region_id(wy, wx, yj, xj);
            #pragma unroll
            for (int ni = 0; ni < 4; ni++) {
                float v;
                if (jok) {
                    float bb = lbias[((yi[ni] - yj + 6) * 13 + (xi[ni] - xj + 6)) * 8 + h];
                    v = s[mi][ni][r] + bb + ((cnti[ni] != cj) ? -100.0f : 0.0f);
                } else {
                    v = -1e30f;
                }
                s[mi][ni][r] = v;
                mx[ni] = fmaxf(mx[ni], v);
            }
        }
    }
    #pragma unroll
    for (int ni = 0; ni < 4; ni++) {
        mx[ni] = fmaxf(mx[ni], __shfl_xor(mx[ni], 16));
        mx[ni] = fmaxf(mx[ni], __shfl_xor(mx[ni], 32));
    }
    float sum[4] = { 0.f, 0.f, 0.f, 0.f };
    #pragma unroll
    for (int mi = 0; mi < 4; mi++)
        #pragma unroll
        for (int ni = 0; ni < 4; ni++)
            #pragma unroll
            for (int r = 0; r < 4; r++) {
                float p = __expf(s[mi][ni][r] - mx[ni]);
                s[mi][ni][r] = p;
                sum[ni] += p;
            }
    #pragma unroll
    for (int ni = 0; ni < 4; ni++) {
        sum[ni] += __shfl_xor(sum[ni], 16);
        sum[ni] += __shfl_xor(sum[ni], 32);
        sum[ni] = 1.0f / sum[ni];
    }
    // pack P rows (pairs along j) to bf16
    unsigned pkd[4][4][2];
    #pragma unroll
    for (int mi = 0; mi < 4; mi++)
        #pragma unroll
        for (int ni = 0; ni < 4; ni++) {
            pkd[mi][ni][0] = pk2bf(s[mi][ni][0] * sum[ni], s[mi][ni][1] * sum[ni]);
            pkd[mi][ni][1] = pk2bf(s[mi][ni][2] * sum[ni], s[mi][ni][3] * sum[ni]);
        }
    // PV: outT[d][i] = sum_j vT[d][j] * P[j][i]; V A-frags via the same shuffle as P
    f32x4 o[2][4];
    #pragma unroll
    for (int md = 0; md < 2; md++)
        #pragma unroll
        for (int ni = 0; ni < 4; ni++) o[md][ni] = (f32x4){0.f, 0.f, 0.f, 0.f};
    #pragma unroll
    for (int ks = 0; ks < 2; ks++) {
        s16x8 bp[4], av[2];
        #pragma unroll
        for (int ni = 0; ni < 4; ni++) {
            unsigned wd[4];
            #pragma unroll
            for (int q = 0; q < 4; q++) {
                int src = (2 * (gl & 1) + (q >> 1)) * 16 + il;
                unsigned v0 = (unsigned)__shfl((int)pkd[2 * ks    ][ni][q & 1], src);
                unsigned v1 = (unsigned)__shfl((int)pkd[2 * ks + 1][ni][q & 1], src);
                wd[q] = (gl & 2) ? v1 : v0;
            }
            union { unsigned u[4]; s16x8 v; } cv;
            cv.u[0] = wd[0]; cv.u[1] = wd[1]; cv.u[2] = wd[2]; cv.u[3] = wd[3];
            bp[ni] = cv.v;
        }
        #pragma unroll
        for (int md = 0; md < 2; md++) {
            unsigned wd[4];
            #pragma unroll
            for (int q = 0; q < 4; q++) {
                int src = (2 * (gl & 1) + (q >> 1)) * 16 + il;
                unsigned v0 = (unsigned)__shfl((int)pv[2 * ks    ][md][q & 1], src);
                unsigned v1 = (unsigned)__shfl((int)pv[2 * ks + 1][md][q & 1], src);
                wd[q] = (gl & 2) ? v1 : v0;
            }
            union { unsigned u[4]; s16x8 v; } cv;
            cv.u[0] = wd[0]; cv.u[1] = wd[1]; cv.u[2] = wd[2]; cv.u[3] = wd[3];
            av[md] = cv.v;
        }
        #pragma unroll
        for (int md = 0; md < 2; md++)
            #pragma unroll
            for (int ni = 0; ni < 4; ni++)
                o[md][ni] = __builtin_amdgcn_mfma_f32_16x16x32_bf16(av[md], bp[ni], o[md][ni], 0, 0, 0);
    }
    // write attention output rows into buf cols 0..255: [t][c=h*32+d]
    #pragma unroll
    for (int md = 0; md < 2; md++)
        #pragma unroll
        for (int ni = 0; ni < 4; ni++) {
            s16x4 pk = { f2bf(o[md][ni][0]), f2bf(o[md][ni][1]), f2bf(o[md][ni][2]), f2bf(o[md][ni][3]) };
            *(s16x4*)&buf[(ni * 16 + il) * LQS + h * 32 + md * 16 + gl * 4] = pk;
        }
    __syncthreads();

    // ---------------- proj GEMM ----------------
    {
        f32x4 acc[4][2];
        #pragma unroll
        for (int mi = 0; mi < 4; mi++)
            #pragma unroll
            for (int ni = 0; ni < 2; ni++) acc[mi][ni] = (f32x4){0.f, 0.f, 0.f, 0.f};
        for (int k0 = 0; k0 < 256; k0 += 32) {
            s16x8 a[4];
            #pragma unroll
            for (int mi = 0; mi < 4; mi++)
                a[mi] = *(const s16x8*)&buf[(mi * 16 + il) * LQS + k0 + 8 * gl];
            #pragma unroll
            for (int ni = 0; ni < 2; ni++) {
                s16x8 bw = *(const s16x8*)(wproj + (32 * w + 16 * ni + il) * 256 + k0 + 8 * gl);
                #pragma unroll
                for (int mi = 0; mi < 4; mi++)
                    acc[mi][ni] = __builtin_amdgcn_mfma_f32_16x16x32_bf16(a[mi], bw, acc[mi][ni], 0, 0, 0);
            }
        }
        __syncthreads();   // proj reads done; buf -> f32 out staging
        float* fout = (float*)smem;   // [49][FOS]
        #pragma unroll
        for (int ni = 0; ni < 2; ni++) {
            int oc = 32 * w + 16 * ni + il;
            float pb = proj_bias[oc];
            #pragma unroll
            for (int mi = 0; mi < 4; mi++)
                #pragma unroll
                for (int r = 0; r < 4; r++) {
                    int t = mi * 16 + gl * 4 + r;
                    if (t < 49) fout[t * FOS + oc] = acc[mi][ni][r] + pb;
                }
        }
        __syncthreads();
        // coalesced store with reverse roll: full 1KB token rows
        for (int i = tid; i < 3136; i += 512) {   // 49 rows x 64 float4 chunks
            int t = i >> 6, c4 = (i & 63) << 2;
            f32x4 v = *(const f32x4*)&fout[t * FOS + c4];
            int ty = t / 7, tx = t % 7;
            int R = wy * 7 + ty + 3; if (R >= 56) R -= 56;
            int C = wx * 7 + tx + 3; if (C >= 56) C -= 56;
            *(f32x4*)(out + (((b * 56 + R) * 56 + C) << 8) + c4) = v;
        }
    }
}

extern "C" void kernel_launch(void* const* d_in, const int* in_sizes, int n_in,
                              void* d_out, int out_size, void* d_ws, size_t ws_size,
                              hipStream_t stream) {
    const float* x   = (const float*)d_in[0];
    const float* qw  = (const float*)d_in[1];
    const float* qb  = (const float*)d_in[2];
    const float* pw  = (const float*)d_in[3];
    const float* pb  = (const float*)d_in[4];
    const float* rpb = (const float*)d_in[5];

    short* wqkv  = (short*)d_ws;            // 768*256 bf16
    short* wproj = wqkv + 768 * 256;        // 256*256 bf16

    wcvt_kernel<<<128, 256, 0, stream>>>(qw, pw, wqkv, wproj);
    swin_kernel<<<2048, 512, 0, stream>>>(x, qb, pb, rpb, wqkv, wproj, (float*)d_out);
}

// Round 4
// 517.221 us; speedup vs baseline: 1.1887x; 1.1887x over previous
//
#include <hip/hip_runtime.h>
#include <hip/hip_bf16.h>

typedef __attribute__((ext_vector_type(4))) float f32x4;
typedef __attribute__((ext_vector_type(8))) short s16x8;
typedef __attribute__((ext_vector_type(4))) short s16x4;

#define LQS 520   // shared buf row stride (bf16 elems): 512 + 8 pad (1040B, 16B-aligned)
#define FOS 260   // f32 out-staging row stride

// smem: one 64x520 bf16 buffer, multi-purpose:
//   phase A: cols 0..255 = x (bf16)
//   phase B: cols 0..255 = Q, cols 256..511 = K   (per-wave private 32-col slices)
//   phase C: cols 256..511 = attention output (overwrites own K cols)
//   phase D: f32[49][260] = proj output staging (overlays everything)
#define SZ_BUF    (64 * LQS * 2)          // 66560
#define OFF_LB    SZ_BUF
#define SZ_LB     (169 * 9 * 4)           // 6084 (stride-9 to avoid bank conflicts)
#define SMEM_BYTES (SZ_BUF + SZ_LB)       // 72644 -> 2 blocks/CU (LDS-wise)

__device__ __forceinline__ short f2bf(float f) {
    unsigned u = __builtin_bit_cast(unsigned, f);
    unsigned r = (u + 0x7FFFu + ((u >> 16) & 1u)) >> 16;
    return (short)r;
}

__device__ __forceinline__ unsigned pk2bf(float a, float b) {
    return (unsigned)(unsigned short)f2bf(a) | ((unsigned)(unsigned short)f2bf(b) << 16);
}

__device__ __forceinline__ int region_id(int wy, int wx, int ty, int tx) {
    int rr = wy * 7 + ty;
    int cc = wx * 7 + tx;
    int rh = (rr < 49) ? 0 : ((rr < 53) ? 1 : 2);
    int rw = (cc < 49) ? 0 : ((cc < 53) ? 1 : 2);
    return rh * 3 + rw;
}

__global__ void wcvt_kernel(const float* __restrict__ qw, const float* __restrict__ pw,
                            short* __restrict__ wqkv, short* __restrict__ wproj) {
    int idx = blockIdx.x * blockDim.x + threadIdx.x;
    int stride = gridDim.x * blockDim.x;
    for (int i = idx; i < 65536; i += stride) {
        if (i < 49152) {
            const f32x4 v = *(const f32x4*)(qw + i * 4);
            s16x4 o = { f2bf(v.x), f2bf(v.y), f2bf(v.z), f2bf(v.w) };
            *(s16x4*)(wqkv + i * 4) = o;
        } else {
            int j = i - 49152;
            const f32x4 v = *(const f32x4*)(pw + j * 4);
            s16x4 o = { f2bf(v.x), f2bf(v.y), f2bf(v.z), f2bf(v.w) };
            *(s16x4*)(wproj + j * 4) = o;
        }
    }
}

__global__ __launch_bounds__(512, 4)
void swin_kernel(const float* __restrict__ x,
                 const float* __restrict__ qkv_bias,
                 const float* __restrict__ proj_bias,
                 const float* __restrict__ rpb,
                 const short* __restrict__ wqkv,
                 const short* __restrict__ wproj,
                 float* __restrict__ out) {
    __shared__ __align__(16) char smem[SMEM_BYTES];
    short* buf   = (short*)smem;
    float* lbias = (float*)(smem + OFF_LB);

    const int tid  = threadIdx.x;
    const int w    = tid >> 6;        // wave id == head id
    const int lane = tid & 63;
    const int il   = lane & 15;
    const int gl   = lane >> 4;

    const int b   = blockIdx.x >> 6;
    const int wid = blockIdx.x & 63;
    const int wy  = wid >> 3, wx = wid & 7;

    // ---------------- stage rpb (stride 9) + window x (bf16, cols 0..255) ----
    for (int i = tid; i < 1352; i += 512) lbias[(i >> 3) * 9 + (i & 7)] = rpb[i];
    for (int i = tid; i < 4096; i += 512) {  // 64 rows x 64 float4 chunks
        int t = i >> 6, c4 = (i & 63) << 2;
        s16x4 o;
        if (t < 49) {
            int ty = t / 7, tx = t % 7;
            int R = wy * 7 + ty + 3; if (R >= 56) R -= 56;
            int C = wx * 7 + tx + 3; if (C >= 56) C -= 56;
            const f32x4 v = *(const f32x4*)(x + (((b * 56 + R) * 56 + C) << 8) + c4);
            o = (s16x4){ f2bf(v.x), f2bf(v.y), f2bf(v.z), f2bf(v.w) };
        } else {
            o = (s16x4){ 0, 0, 0, 0 };
        }
        *(s16x4*)&buf[t * LQS + c4] = o;
    }
    __syncthreads();   // (1)

    // ---------------- QKV pass 1: V (32 accs) -> packed regs ----------------
    unsigned pv[4][2][2];
    {
        f32x4 vacc[4][2];
        #pragma unroll
        for (int mi = 0; mi < 4; mi++)
            #pragma unroll
            for (int md = 0; md < 2; md++) vacc[mi][md] = (f32x4){0.f, 0.f, 0.f, 0.f};
        for (int k0 = 0; k0 < 256; k0 += 32) {
            s16x8 a[4];
            #pragma unroll
            for (int mi = 0; mi < 4; mi++)
                a[mi] = *(const s16x8*)&buf[(mi * 16 + il) * LQS + k0 + 8 * gl];
            #pragma unroll
            for (int md = 0; md < 2; md++) {
                s16x8 bfr = *(const s16x8*)(wqkv + (512 + 32 * w + 16 * md + il) * 256 + k0 + 8 * gl);
                #pragma unroll
                for (int mi = 0; mi < 4; mi++)
                    vacc[mi][md] = __builtin_amdgcn_mfma_f32_16x16x32_bf16(a[mi], bfr, vacc[mi][md], 0, 0, 0);
            }
        }
        #pragma unroll
        for (int md = 0; md < 2; md++) {
            float bv = qkv_bias[512 + 32 * w + 16 * md + il];
            #pragma unroll
            for (int mi = 0; mi < 4; mi++) {
                pv[mi][md][0] = pk2bf(vacc[mi][md][0] + bv, vacc[mi][md][1] + bv);
                pv[mi][md][1] = pk2bf(vacc[mi][md][2] + bv, vacc[mi][md][3] + bv);
            }
        }
    }

    // ---------------- QKV pass 2: Q,K (64 accs) ----------------
    {
        f32x4 acc[4][4];
        #pragma unroll
        for (int mi = 0; mi < 4; mi++)
            #pragma unroll
            for (int ni = 0; ni < 4; ni++) acc[mi][ni] = (f32x4){0.f, 0.f, 0.f, 0.f};
        for (int k0 = 0; k0 < 256; k0 += 32) {
            s16x8 a[4];
            #pragma unroll
            for (int mi = 0; mi < 4; mi++)
                a[mi] = *(const s16x8*)&buf[(mi * 16 + il) * LQS + k0 + 8 * gl];
            #pragma unroll
            for (int ni = 0; ni < 4; ni++) {
                int col = (ni < 2) ? (32 * w + 16 * ni) : (256 + 32 * w + 16 * (ni - 2));
                s16x8 bfr = *(const s16x8*)(wqkv + (col + il) * 256 + k0 + 8 * gl);
                #pragma unroll
                for (int mi = 0; mi < 4; mi++)
                    acc[mi][ni] = __builtin_amdgcn_mfma_f32_16x16x32_bf16(a[mi], bfr, acc[mi][ni], 0, 0, 0);
            }
        }
        __syncthreads();   // (2) all x reads done; buf -> Q|K (per-wave private cols)
        #pragma unroll
        for (int ni = 0; ni < 4; ni++) {
            int col = ((ni < 2) ? (32 * w + 16 * ni) : (256 + 32 * w + 16 * (ni - 2))) + il;
            float bv = qkv_bias[(ni < 2) ? col : (col - 256 + 256)];  // qkv_bias index: q cols as-is, k cols +256 base handled below
            // note: for ni>=2 the weight col used above was (256+32w+16(ni-2)), bias index matches that
            bv = qkv_bias[(ni < 2) ? (32 * w + 16 * ni + il) : (256 + 32 * w + 16 * (ni - 2) + il)];
            float scl = (ni < 2) ? 0.17677669529663687f : 1.0f;
            #pragma unroll
            for (int mi = 0; mi < 4; mi++)
                #pragma unroll
                for (int r = 0; r < 4; r++)
                    buf[(mi * 16 + gl * 4 + r) * LQS + col] = f2bf((acc[mi][ni][r] + bv) * scl);
        }
    }
    // no barrier: wave reads back only its own columns (lgkmcnt ordering within wave)

    // ---------------- attention, head h = w ----------------
    const int h = w;
    f32x4 s[4][4];
    {
        s16x8 bq[4];
        #pragma unroll
        for (int ni = 0; ni < 4; ni++)
            bq[ni] = *(const s16x8*)&buf[(ni * 16 + il) * LQS + 32 * h + 8 * gl];
        #pragma unroll
        for (int mi = 0; mi < 4; mi++) {
            s16x8 ak = *(const s16x8*)&buf[(mi * 16 + il) * LQS + 256 + 32 * h + 8 * gl];
            #pragma unroll
            for (int ni = 0; ni < 4; ni++)
                s[mi][ni] = __builtin_amdgcn_mfma_f32_16x16x32_bf16(ak, bq[ni], (f32x4){0.f,0.f,0.f,0.f}, 0, 0, 0);
        }
    }
    // s[mi][ni][r] = score[ query i = ni*16+il ][ key j = mi*16+gl*4+r ]
    int base9[4], cnti[4];
    #pragma unroll
    for (int ni = 0; ni < 4; ni++) {
        int i = ni * 16 + il; int ic = i > 48 ? 48 : i;
        int yi = ic / 7, xi = ic % 7;
        base9[ni] = (yi * 13 + xi + 84) * 9 + h;
        cnti[ni] = region_id(wy, wx, yi, xi);
    }
    float mx[4] = { -1e30f, -1e30f, -1e30f, -1e30f };
    #pragma unroll
    for (int mi = 0; mi < 4; mi++) {
        #pragma unroll
        for (int r = 0; r < 4; r++) {
            int j = mi * 16 + gl * 4 + r;
            bool jok = (j < 49);
            int jc = jok ? j : 48;
            int yj = jc / 7, xj = jc % 7;
            int bj9 = (yj * 13 + xj) * 9;
            int cj = region_id(wy, wx, yj, xj);
            #pragma unroll
            for (int ni = 0; ni < 4; ni++) {
                float v;
                if (jok) {
                    float bb = lbias[base9[ni] - bj9];
                    v = s[mi][ni][r] + bb + ((cnti[ni] != cj) ? -100.0f : 0.0f);
                } else {
                    v = -1e30f;
                }
                s[mi][ni][r] = v;
                mx[ni] = fmaxf(mx[ni], v);
            }
        }
    }
    #pragma unroll
    for (int ni = 0; ni < 4; ni++) {
        mx[ni] = fmaxf(mx[ni], __shfl_xor(mx[ni], 16));
        mx[ni] = fmaxf(mx[ni], __shfl_xor(mx[ni], 32));
    }
    float sum[4] = { 0.f, 0.f, 0.f, 0.f };
    #pragma unroll
    for (int mi = 0; mi < 4; mi++)
        #pragma unroll
        for (int ni = 0; ni < 4; ni++)
            #pragma unroll
            for (int r = 0; r < 4; r++) {
                float p = __expf(s[mi][ni][r] - mx[ni]);
                s[mi][ni][r] = p;
                sum[ni] += p;
            }
    #pragma unroll
    for (int ni = 0; ni < 4; ni++) {
        sum[ni] += __shfl_xor(sum[ni], 16);
        sum[ni] += __shfl_xor(sum[ni], 32);
        sum[ni] = 1.0f / sum[ni];
    }

    // PV per key-half: pack W transiently, shuffle to frags, accumulate o
    f32x4 o[2][4];
    #pragma unroll
    for (int md = 0; md < 2; md++)
        #pragma unroll
        for (int ni = 0; ni < 4; ni++) o[md][ni] = (f32x4){0.f, 0.f, 0.f, 0.f};
    #pragma unroll
    for (int ks = 0; ks < 2; ks++) {
        s16x8 av[2];
        #pragma unroll
        for (int md = 0; md < 2; md++) {
            unsigned wd[4];
            #pragma unroll
            for (int q = 0; q < 4; q++) {
                int src = (2 * (gl & 1) + (q >> 1)) * 16 + il;
                unsigned v0 = (unsigned)__shfl((int)pv[2 * ks    ][md][q & 1], src);
                unsigned v1 = (unsigned)__shfl((int)pv[2 * ks + 1][md][q & 1], src);
                wd[q] = (gl & 2) ? v1 : v0;
            }
            union { unsigned u[4]; s16x8 v; } cv;
            cv.u[0] = wd[0]; cv.u[1] = wd[1]; cv.u[2] = wd[2]; cv.u[3] = wd[3];
            av[md] = cv.v;
        }
        #pragma unroll
        for (int ni = 0; ni < 4; ni++) {
            unsigned w0[2], w1[2];
            w0[0] = pk2bf(s[2 * ks][ni][0] * sum[ni], s[2 * ks][ni][1] * sum[ni]);
            w0[1] = pk2bf(s[2 * ks][ni][2] * sum[ni], s[2 * ks][ni][3] * sum[ni]);
            w1[0] = pk2bf(s[2 * ks + 1][ni][0] * sum[ni], s[2 * ks + 1][ni][1] * sum[ni]);
            w1[1] = pk2bf(s[2 * ks + 1][ni][2] * sum[ni], s[2 * ks + 1][ni][3] * sum[ni]);
            unsigned wd[4];
            #pragma unroll
            for (int q = 0; q < 4; q++) {
                int src = (2 * (gl & 1) + (q >> 1)) * 16 + il;
                unsigned v0 = (unsigned)__shfl((int)w0[q & 1], src);
                unsigned v1 = (unsigned)__shfl((int)w1[q & 1], src);
                wd[q] = (gl & 2) ? v1 : v0;
            }
            union { unsigned u[4]; s16x8 v; } cv;
            cv.u[0] = wd[0]; cv.u[1] = wd[1]; cv.u[2] = wd[2]; cv.u[3] = wd[3];
            #pragma unroll
            for (int md = 0; md < 2; md++)
                o[md][ni] = __builtin_amdgcn_mfma_f32_16x16x32_bf16(av[md], cv.v, o[md][ni], 0, 0, 0);
        }
    }
    // write attention output into own K cols (256 + 32h ..): [t][256 + h*32 + d]
    #pragma unroll
    for (int md = 0; md < 2; md++)
        #pragma unroll
        for (int ni = 0; ni < 4; ni++) {
            s16x4 pk = { f2bf(o[md][ni][0]), f2bf(o[md][ni][1]), f2bf(o[md][ni][2]), f2bf(o[md][ni][3]) };
            *(s16x4*)&buf[(ni * 16 + il) * LQS + 256 + h * 32 + md * 16 + gl * 4] = pk;
        }
    __syncthreads();   // (3) attn-out complete before cross-wave proj reads

    // ---------------- proj GEMM + staged coalesced store ----------------
    {
        f32x4 acc[4][2];
        #pragma unroll
        for (int mi = 0; mi < 4; mi++)
            #pragma unroll
            for (int ni = 0; ni < 2; ni++) acc[mi][ni] = (f32x4){0.f, 0.f, 0.f, 0.f};
        for (int k0 = 0; k0 < 256; k0 += 32) {
            s16x8 a[4];
            #pragma unroll
            for (int mi = 0; mi < 4; mi++)
                a[mi] = *(const s16x8*)&buf[(mi * 16 + il) * LQS + 256 + k0 + 8 * gl];
            #pragma unroll
            for (int ni = 0; ni < 2; ni++) {
                s16x8 bw = *(const s16x8*)(wproj + (32 * w + 16 * ni + il) * 256 + k0 + 8 * gl);
                #pragma unroll
                for (int mi = 0; mi < 4; mi++)
                    acc[mi][ni] = __builtin_amdgcn_mfma_f32_16x16x32_bf16(a[mi], bw, acc[mi][ni], 0, 0, 0);
            }
        }
        __syncthreads();   // (4) proj reads done; buf -> f32 out staging
        float* fout = (float*)smem;   // [49][FOS]
        #pragma unroll
        for (int ni = 0; ni < 2; ni++) {
            int oc = 32 * w + 16 * ni + il;
            float pb = proj_bias[oc];
            #pragma unroll
            for (int mi = 0; mi < 4; mi++)
                #pragma unroll
                for (int r = 0; r < 4; r++) {
                    int t = mi * 16 + gl * 4 + r;
                    if (t < 49) fout[t * FOS + oc] = acc[mi][ni][r] + pb;
                }
        }
        __syncthreads();   // (5)
        for (int i = tid; i < 3136; i += 512) {   // 49 rows x 64 float4 chunks
            int t = i >> 6, c4 = (i & 63) << 2;
            f32x4 v = *(const f32x4*)&fout[t * FOS + c4];
            int ty = t / 7, tx = t % 7;
            int R = wy * 7 + ty + 3; if (R >= 56) R -= 56;
            int C = wx * 7 + tx + 3; if (C >= 56) C -= 56;
            *(f32x4*)(out + (((b * 56 + R) * 56 + C) << 8) + c4) = v;
        }
    }
}

extern "C" void kernel_launch(void* const* d_in, const int* in_sizes, int n_in,
                              void* d_out, int out_size, void* d_ws, size_t ws_size,
                              hipStream_t stream) {
    const float* x   = (const float*)d_in[0];
    const float* qw  = (const float*)d_in[1];
    const float* qb  = (const float*)d_in[2];
    const float* pw  = (const float*)d_in[3];
    const float* pb  = (const float*)d_in[4];
    const float* rpb = (const float*)d_in[5];

    short* wqkv  = (short*)d_ws;            // 768*256 bf16
    short* wproj = wqkv + 768 * 256;        // 256*256 bf16

    wcvt_kernel<<<128, 256, 0, stream>>>(qw, pw, wqkv, wproj);
    swin_kernel<<<2048, 512, 0, stream>>>(x, qb, pb, rpb, wqkv, wproj, (float*)d_out);
}

// Round 5
// 231.493 us; speedup vs baseline: 2.6560x; 2.2343x over previous
//
#include <hip/hip_runtime.h>
#include <hip/hip_bf16.h>

typedef __attribute__((ext_vector_type(4))) float f32x4;
typedef __attribute__((ext_vector_type(8))) short s16x8;
typedef __attribute__((ext_vector_type(4))) short s16x4;

#define LQS 520       // region A as bf16 [64][520]: x / Q|K
#define FOS 260       // region A as f32  [64][260]: attn f32 reduce, proj fout
#define VTS 72        // region B: VT [256 vcols][72] shorts
#define LAS 264       // region B: la (attn bf16) [64][264] shorts

#define OFF_A    0
#define SZ_A     (64 * LQS * 2)            // 66560
#define OFF_B    (OFF_A + SZ_A)
#define SZ_B     (256 * VTS * 2)           // 36864 (>= 64*264*2 = 33792 for la)
#define OFF_BIAS (OFF_B + SZ_B)            // 103424
#define SZ_BIAS  6096                      // 169*9*4 = 6084, padded
#define OFF_ML   (OFF_BIAS + SZ_BIAS)      // 109520
#define SZ_ML    (8 * 2 * 64 * 2 * 4)      // 8192: [head][jh][i][m,l]
#define SMEM_BYTES (OFF_ML + SZ_ML)        // 117712 -> 1 block/CU, 16 waves

__device__ __forceinline__ short f2bf(float f) {
    unsigned u = __builtin_bit_cast(unsigned, f);
    unsigned r = (u + 0x7FFFu + ((u >> 16) & 1u)) >> 16;
    return (short)r;
}

__device__ __forceinline__ unsigned pk2bf(float a, float b) {
    return (unsigned)(unsigned short)f2bf(a) | ((unsigned)(unsigned short)f2bf(b) << 16);
}

__device__ __forceinline__ int region_id(int wy, int wx, int ty, int tx) {
    int rr = wy * 7 + ty;
    int cc = wx * 7 + tx;
    int rh = (rr < 49) ? 0 : ((rr < 53) ? 1 : 2);
    int rw = (cc < 49) ? 0 : ((cc < 53) ? 1 : 2);
    return rh * 3 + rw;
}

__global__ void wcvt_kernel(const float* __restrict__ qw, const float* __restrict__ pw,
                            short* __restrict__ wqkv, short* __restrict__ wproj) {
    int idx = blockIdx.x * blockDim.x + threadIdx.x;
    int stride = gridDim.x * blockDim.x;
    for (int i = idx; i < 65536; i += stride) {
        if (i < 49152) {
            const f32x4 v = *(const f32x4*)(qw + i * 4);
            s16x4 o = { f2bf(v.x), f2bf(v.y), f2bf(v.z), f2bf(v.w) };
            *(s16x4*)(wqkv + i * 4) = o;
        } else {
            int j = i - 49152;
            const f32x4 v = *(const f32x4*)(pw + j * 4);
            s16x4 o = { f2bf(v.x), f2bf(v.y), f2bf(v.z), f2bf(v.w) };
            *(s16x4*)(wproj + j * 4) = o;
        }
    }
}

__global__ __launch_bounds__(1024, 4)
void swin_kernel(const float* __restrict__ x,
                 const float* __restrict__ qkv_bias,
                 const float* __restrict__ proj_bias,
                 const float* __restrict__ rpb,
                 const short* __restrict__ wqkv,
                 const short* __restrict__ wproj,
                 float* __restrict__ out) {
    __shared__ __align__(16) char smem[SMEM_BYTES];
    short* lqk   = (short*)(smem + OFF_A);    // x, then Q|K (bf16)
    float* lout  = (float*)(smem + OFF_A);    // f32 attn reduce / fout
    short* lvt   = (short*)(smem + OFF_B);    // VT, then la
    short* la    = (short*)(smem + OFF_B);
    float* lbias = (float*)(smem + OFF_BIAS);
    float* lml   = (float*)(smem + OFF_ML);

    const int tid  = threadIdx.x;
    const int w    = tid >> 6;        // wave id in [0,16)
    const int lane = tid & 63;
    const int il   = lane & 15;
    const int gl   = lane >> 4;
    const int hh   = w >> 1;          // head
    const int jh   = w & 1;           // key-half

    const int b   = blockIdx.x >> 6;
    const int wid = blockIdx.x & 63;
    const int wy  = wid >> 3, wx = wid & 7;

    // ---------------- stage rpb (stride 9) + window x (bf16, cols 0..255) ----
    for (int i = tid; i < 1352; i += 1024) lbias[(i >> 3) * 9 + (i & 7)] = rpb[i];
    for (int i = tid; i < 4096; i += 1024) {  // 64 rows x 64 float4 chunks
        int t = i >> 6, c4 = (i & 63) << 2;
        s16x4 o;
        if (t < 49) {
            int ty = t / 7, tx = t % 7;
            int R = wy * 7 + ty + 3; if (R >= 56) R -= 56;
            int C = wx * 7 + tx + 3; if (C >= 56) C -= 56;
            const f32x4 v = *(const f32x4*)(x + (((b * 56 + R) * 56 + C) << 8) + c4);
            o = (s16x4){ f2bf(v.x), f2bf(v.y), f2bf(v.z), f2bf(v.w) };
        } else {
            o = (s16x4){ 0, 0, 0, 0 };
        }
        *(s16x4*)&lqk[t * LQS + c4] = o;
    }
    __syncthreads();   // (1)

    // ---------------- QKV GEMM: wave w -> Q,K,V col-tile [16w,16w+16) ------
    {
        f32x4 acc[4][3];
        #pragma unroll
        for (int mi = 0; mi < 4; mi++)
            #pragma unroll
            for (int t = 0; t < 3; t++) acc[mi][t] = (f32x4){0.f, 0.f, 0.f, 0.f};
        for (int k0 = 0; k0 < 256; k0 += 32) {
            s16x8 a[4];
            #pragma unroll
            for (int mi = 0; mi < 4; mi++)
                a[mi] = *(const s16x8*)&lqk[(mi * 16 + il) * LQS + k0 + 8 * gl];
            #pragma unroll
            for (int t = 0; t < 3; t++) {
                s16x8 bfr = *(const s16x8*)(wqkv + (t * 256 + 16 * w + il) * 256 + k0 + 8 * gl);
                #pragma unroll
                for (int mi = 0; mi < 4; mi++)
                    acc[mi][t] = __builtin_amdgcn_mfma_f32_16x16x32_bf16(a[mi], bfr, acc[mi][t], 0, 0, 0);
            }
        }
        // V -> VT LDS (region B, transposed; r-contiguous tokens -> 8B chunks)
        {
            float bv = qkv_bias[512 + 16 * w + il];
            #pragma unroll
            for (int mi = 0; mi < 4; mi++) {
                s16x4 pk = { f2bf(acc[mi][2][0] + bv), f2bf(acc[mi][2][1] + bv),
                             f2bf(acc[mi][2][2] + bv), f2bf(acc[mi][2][3] + bv) };
                *(s16x4*)&lvt[(16 * w + il) * VTS + mi * 16 + gl * 4] = pk;
            }
        }
        __syncthreads();   // (2) x reads done everywhere; region A -> Q|K
        {
            float bq_ = qkv_bias[16 * w + il];
            float bk_ = qkv_bias[256 + 16 * w + il];
            #pragma unroll
            for (int mi = 0; mi < 4; mi++)
                #pragma unroll
                for (int r = 0; r < 4; r++) {
                    int row = mi * 16 + gl * 4 + r;
                    lqk[row * LQS + 16 * w + il] = f2bf((acc[mi][0][r] + bq_) * 0.17677669529663687f);
                    lqk[row * LQS + 256 + 16 * w + il] = f2bf(acc[mi][1][r] + bk_);
                }
        }
    }
    __syncthreads();   // (3) Q,K ready

    // ---------------- attention: wave (hh, jh), keys j in [32jh, 32jh+32) ---
    f32x4 s[2][4];
    {
        s16x8 bq[4], ak[2];
        #pragma unroll
        for (int ni = 0; ni < 4; ni++)
            bq[ni] = *(const s16x8*)&lqk[(ni * 16 + il) * LQS + 32 * hh + 8 * gl];
        #pragma unroll
        for (int mi = 0; mi < 2; mi++)
            ak[mi] = *(const s16x8*)&lqk[(jh * 32 + mi * 16 + il) * LQS + 256 + 32 * hh + 8 * gl];
        #pragma unroll
        for (int mi = 0; mi < 2; mi++)
            #pragma unroll
            for (int ni = 0; ni < 4; ni++)
                s[mi][ni] = __builtin_amdgcn_mfma_f32_16x16x32_bf16(ak[mi], bq[ni], (f32x4){0.f,0.f,0.f,0.f}, 0, 0, 0);
    }
    // s[mi][ni][r] = score[ i = ni*16+il ][ j = 32jh + mi*16 + gl*4 + r ]
    int base9[4], cnti[4];
    #pragma unroll
    for (int ni = 0; ni < 4; ni++) {
        int i = ni * 16 + il; int ic = i > 48 ? 48 : i;
        int yi = ic / 7, xi = ic % 7;
        base9[ni] = (yi * 13 + xi + 84) * 9 + hh;
        cnti[ni] = region_id(wy, wx, yi, xi);
    }
    float mx[4] = { -1e30f, -1e30f, -1e30f, -1e30f };
    #pragma unroll
    for (int mi = 0; mi < 2; mi++) {
        #pragma unroll
        for (int r = 0; r < 4; r++) {
            int j = 32 * jh + mi * 16 + gl * 4 + r;
            bool jok = (j < 49);
            int jc = jok ? j : 48;
            int yj = jc / 7, xj = jc % 7;
            int bj9 = (yj * 13 + xj) * 9;
            int cj = region_id(wy, wx, yj, xj);
            #pragma unroll
            for (int ni = 0; ni < 4; ni++) {
                float v;
                if (jok) {
                    float bb = lbias[base9[ni] - bj9];
                    v = s[mi][ni][r] + bb + ((cnti[ni] != cj) ? -100.0f : 0.0f);
                } else {
                    v = -1e30f;
                }
                s[mi][ni][r] = v;
                mx[ni] = fmaxf(mx[ni], v);
            }
        }
    }
    #pragma unroll
    for (int ni = 0; ni < 4; ni++) {
        mx[ni] = fmaxf(mx[ni], __shfl_xor(mx[ni], 16));
        mx[ni] = fmaxf(mx[ni], __shfl_xor(mx[ni], 32));
    }
    float sm[4] = { 0.f, 0.f, 0.f, 0.f };
    #pragma unroll
    for (int mi = 0; mi < 2; mi++)
        #pragma unroll
        for (int ni = 0; ni < 4; ni++)
            #pragma unroll
            for (int r = 0; r < 4; r++) {
                float p = __expf(s[mi][ni][r] - mx[ni]);
                s[mi][ni][r] = p;
                sm[ni] += p;
            }
    #pragma unroll
    for (int ni = 0; ni < 4; ni++) {
        sm[ni] += __shfl_xor(sm[ni], 16);
        sm[ni] += __shfl_xor(sm[ni], 32);
    }
    // exchange (m,l) with partner half
    if (gl == 0) {
        #pragma unroll
        for (int ni = 0; ni < 4; ni++) {
            int idx = ((hh * 2 + jh) * 64 + ni * 16 + il) * 2;
            lml[idx] = mx[ni];
            lml[idx + 1] = sm[ni];
        }
    }
    __syncthreads();   // (4)  [also releases region A for lout]
    float scale[4];
    #pragma unroll
    for (int ni = 0; ni < 4; ni++) {
        int idx = ((hh * 2 + (jh ^ 1)) * 64 + ni * 16 + il) * 2;
        float m_o = lml[idx], l_o = lml[idx + 1];
        float m_g = fmaxf(mx[ni], m_o);
        float l_g = sm[ni] * __expf(mx[ni] - m_g) + l_o * __expf(m_o - m_g);
        scale[ni] = __expf(mx[ni] - m_g) / l_g;
    }
    // pack P (bf16 pairs along j), shuffle to B-frags, single-step PV
    f32x4 o[2][4];
    {
        unsigned pkd[2][4][2];
        #pragma unroll
        for (int mi = 0; mi < 2; mi++)
            #pragma unroll
            for (int ni = 0; ni < 4; ni++) {
                pkd[mi][ni][0] = pk2bf(s[mi][ni][0] * scale[ni], s[mi][ni][1] * scale[ni]);
                pkd[mi][ni][1] = pk2bf(s[mi][ni][2] * scale[ni], s[mi][ni][3] * scale[ni]);
            }
        s16x8 av[2];
        #pragma unroll
        for (int md = 0; md < 2; md++)
            av[md] = *(const s16x8*)&lvt[(32 * hh + md * 16 + il) * VTS + jh * 32 + 8 * gl];
        #pragma unroll
        for (int ni = 0; ni < 4; ni++) {
            unsigned wd[4];
            #pragma unroll
            for (int q = 0; q < 4; q++) {
                int src = (2 * (gl & 1) + (q >> 1)) * 16 + il;
                unsigned v0 = (unsigned)__shfl((int)pkd[0][ni][q & 1], src);
                unsigned v1 = (unsigned)__shfl((int)pkd[1][ni][q & 1], src);
                wd[q] = (gl & 2) ? v1 : v0;
            }
            union { unsigned u[4]; s16x8 v; } cv;
            cv.u[0] = wd[0]; cv.u[1] = wd[1]; cv.u[2] = wd[2]; cv.u[3] = wd[3];
            #pragma unroll
            for (int md = 0; md < 2; md++)
                o[md][ni] = __builtin_amdgcn_mfma_f32_16x16x32_bf16(av[md], cv.v, (f32x4){0.f,0.f,0.f,0.f}, 0, 0, 0);
        }
    }
    // cross-pair reduce: jh0 writes f32, jh1 adds and emits bf16 la
    if (jh == 0) {
        #pragma unroll
        for (int md = 0; md < 2; md++)
            #pragma unroll
            for (int ni = 0; ni < 4; ni++)
                *(f32x4*)&lout[(ni * 16 + il) * FOS + 32 * hh + md * 16 + gl * 4] = o[md][ni];
    }
    __syncthreads();   // (5)
    if (jh == 1) {
        #pragma unroll
        for (int md = 0; md < 2; md++)
            #pragma unroll
            for (int ni = 0; ni < 4; ni++) {
                f32x4 t = *(const f32x4*)&lout[(ni * 16 + il) * FOS + 32 * hh + md * 16 + gl * 4];
                t.x += o[md][ni][0]; t.y += o[md][ni][1];
                t.z += o[md][ni][2]; t.w += o[md][ni][3];
                s16x4 pk = { f2bf(t.x), f2bf(t.y), f2bf(t.z), f2bf(t.w) };
                *(s16x4*)&la[(ni * 16 + il) * LAS + 32 * hh + md * 16 + gl * 4] = pk;
            }
    }
    __syncthreads();   // (6) la ready, lout dead

    // ---------------- proj GEMM: wave w -> out cols [16w,16w+16) ------------
    {
        f32x4 acc[4];
        #pragma unroll
        for (int mi = 0; mi < 4; mi++) acc[mi] = (f32x4){0.f, 0.f, 0.f, 0.f};
        for (int k0 = 0; k0 < 256; k0 += 32) {
            s16x8 bw = *(const s16x8*)(wproj + (16 * w + il) * 256 + k0 + 8 * gl);
            #pragma unroll
            for (int mi = 0; mi < 4; mi++) {
                s16x8 a = *(const s16x8*)&la[(mi * 16 + il) * LAS + k0 + 8 * gl];
                acc[mi] = __builtin_amdgcn_mfma_f32_16x16x32_bf16(a, bw, acc[mi], 0, 0, 0);
            }
        }
        float pb = proj_bias[16 * w + il];
        float* fout = lout;   // region A reuse (all lout reads done pre-(6))
        #pragma unroll
        for (int mi = 0; mi < 4; mi++)
            #pragma unroll
            for (int r = 0; r < 4; r++) {
                int t = mi * 16 + gl * 4 + r;
                if (t < 49) fout[t * FOS + 16 * w + il] = acc[mi][r] + pb;
            }
    }
    __syncthreads();   // (7)
    // coalesced store with reverse roll: full 1KB token rows
    for (int i = tid; i < 3136; i += 1024) {   // 49 rows x 64 float4 chunks
        int t = i >> 6, c4 = (i & 63) << 2;
        f32x4 v = *(const f32x4*)&lout[t * FOS + c4];
        int ty = t / 7, tx = t % 7;
        int R = wy * 7 + ty + 3; if (R >= 56) R -= 56;
        int C = wx * 7 + tx + 3; if (C >= 56) C -= 56;
        *(f32x4*)(out + (((b * 56 + R) * 56 + C) << 8) + c4) = v;
    }
}

extern "C" void kernel_launch(void* const* d_in, const int* in_sizes, int n_in,
                              void* d_out, int out_size, void* d_ws, size_t ws_size,
                              hipStream_t stream) {
    const float* x   = (const float*)d_in[0];
    const float* qw  = (const float*)d_in[1];
    const float* qb  = (const float*)d_in[2];
    const float* pw  = (const float*)d_in[3];
    const float* pb  = (const float*)d_in[4];
    const float* rpb = (const float*)d_in[5];

    short* wqkv  = (short*)d_ws;            // 768*256 bf16
    short* wproj = wqkv + 768 * 256;        // 256*256 bf16

    wcvt_kernel<<<128, 256, 0, stream>>>(qw, pw, wqkv, wproj);
    swin_kernel<<<2048, 1024, 0, stream>>>(x, qb, pb, rpb, wqkv, wproj, (float*)d_out);
}

// Round 6
// 231.314 us; speedup vs baseline: 2.6580x; 1.0008x over previous
//
#include <hip/hip_runtime.h>
#include <hip/hip_bf16.h>

typedef __attribute__((ext_vector_type(4))) float f32x4;
typedef __attribute__((ext_vector_type(8))) short s16x8;
typedef __attribute__((ext_vector_type(4))) short s16x4;

#define LQS 520       // region A as bf16 [64][520]: x / Q|K
#define FOS 260       // region A as f32  [64][260]: attn f32 reduce, proj fout
#define VTS 72        // region B: VT [256 vcols][72] shorts (144B rows: 16B-aligned, 2-way banks = free)
#define LAS 264       // region B: la (attn bf16) [64][264] shorts

#define OFF_A    0
#define SZ_A     (64 * LQS * 2)            // 66560
#define OFF_B    (OFF_A + SZ_A)
#define SZ_B     (256 * VTS * 2)           // 36864
#define OFF_ML   (OFF_B + SZ_B)
#define SZ_ML    (8 * 64 * 4)              // 2048: l0 per [head][i]
#define SMEM_BYTES (OFF_ML + SZ_ML)        // 105472 -> 1 block/CU, 16 waves

// v_cvt_pk_bf16_f32: a -> low16, b -> high16 (RNE)
__device__ __forceinline__ unsigned cvt2bf(float a, float b) {
    unsigned r;
    asm("v_cvt_pk_bf16_f32 %0, %1, %2" : "=v"(r) : "v"(a), "v"(b));
    return r;
}

// K0: convert weights fp32 -> bf16 into workspace
__global__ void wcvt_kernel(const float* __restrict__ qw, const float* __restrict__ pw,
                            short* __restrict__ wqkv, short* __restrict__ wproj) {
    int idx = blockIdx.x * blockDim.x + threadIdx.x;
    int stride = gridDim.x * blockDim.x;
    for (int i = idx; i < 65536; i += stride) {
        const float* src = (i < 49152) ? (qw + i * 4) : (pw + (i - 49152) * 4);
        unsigned* dst = (unsigned*)((i < 49152) ? (wqkv + i * 4) : (wproj + (i - 49152) * 4));
        const f32x4 v = *(const f32x4*)src;
        uint2 o = { cvt2bf(v.x, v.y), cvt2bf(v.z, v.w) };
        *(uint2*)dst = o;
    }
}

// K1: bias+mask table, log2-domain. bm[cls][head][i][j], cls = (wy==7)*2 + (wx==7)
__global__ void bmgen_kernel(const float* __restrict__ rpb, float* __restrict__ bm) {
    int idx = blockIdx.x * blockDim.x + threadIdx.x;   // 4*8*64*64 = 131072
    if (idx >= 131072) return;
    int j = idx & 63;
    int i = (idx >> 6) & 63;
    int h = (idx >> 12) & 7;
    int c = idx >> 15;
    int cy = c >> 1, cx = c & 1;
    float v;
    if (j >= 49) {
        v = -1e9f;
    } else {
        int ic = i > 48 ? 48 : i;
        int yi = ic / 7, xi = ic % 7;
        int yj = j / 7, xj = j % 7;
        float bias = rpb[((yi - yj + 6) * 13 + (xi - xj + 6)) * 8 + h];
        int ri = (cy ? (yi < 4 ? 1 : 2) : 0) * 3 + (cx ? (xi < 4 ? 1 : 2) : 0);
        int rj = (cy ? (yj < 4 ? 1 : 2) : 0) * 3 + (cx ? (xj < 4 ? 1 : 2) : 0);
        float mask = (ri != rj) ? -100.0f : 0.0f;
        v = (bias + mask) * 1.4426950408889634f;
    }
    bm[idx] = v;
}

__global__ __launch_bounds__(1024, 4)
void swin_kernel(const float* __restrict__ x,
                 const float* __restrict__ qkv_bias,
                 const float* __restrict__ proj_bias,
                 const short* __restrict__ wqkv,
                 const short* __restrict__ wproj,
                 const float* __restrict__ bm,
                 float* __restrict__ out) {
    __shared__ __align__(16) char smem[SMEM_BYTES];
    short* lqk   = (short*)(smem + OFF_A);    // x, then Q|K (bf16)
    float* lout  = (float*)(smem + OFF_A);    // f32 attn reduce / fout
    short* lvt   = (short*)(smem + OFF_B);    // VT, then la
    short* la    = (short*)(smem + OFF_B);
    float* lml   = (float*)(smem + OFF_ML);   // l0 per [head][i]

    const int tid  = threadIdx.x;
    const int w    = tid >> 6;        // wave id in [0,16)
    const int lane = tid & 63;
    const int il   = lane & 15;
    const int gl   = lane >> 4;
    const int hh   = w >> 1;          // head
    const int jh   = w & 1;           // key-half

    const int b   = blockIdx.x >> 6;
    const int wid = blockIdx.x & 63;
    const int wy  = wid >> 3, wx = wid & 7;

    // ---------------- stage window x (bf16, cols 0..255) ----------------
    for (int i = tid; i < 4096; i += 1024) {  // 64 rows x 64 float4 chunks
        int t = i >> 6, c4 = (i & 63) << 2;
        uint2 o;
        if (t < 49) {
            int ty = t / 7, tx = t % 7;
            int R = wy * 7 + ty + 3; if (R >= 56) R -= 56;
            int C = wx * 7 + tx + 3; if (C >= 56) C -= 56;
            const f32x4 v = *(const f32x4*)(x + (((b * 56 + R) * 56 + C) << 8) + c4);
            o.x = cvt2bf(v.x, v.y); o.y = cvt2bf(v.z, v.w);
        } else {
            o.x = 0; o.y = 0;
        }
        *(uint2*)&lqk[t * LQS + c4] = o;
    }
    __syncthreads();   // (1)

    // ---------------- QKV GEMM: wave w -> Q,K,V col-tile [16w,16w+16) ------
    {
        f32x4 acc[4][3];
        #pragma unroll
        for (int mi = 0; mi < 4; mi++)
            #pragma unroll
            for (int t = 0; t < 3; t++) acc[mi][t] = (f32x4){0.f, 0.f, 0.f, 0.f};
        for (int k0 = 0; k0 < 256; k0 += 32) {
            s16x8 a[4];
            #pragma unroll
            for (int mi = 0; mi < 4; mi++)
                a[mi] = *(const s16x8*)&lqk[(mi * 16 + il) * LQS + k0 + 8 * gl];
            #pragma unroll
            for (int t = 0; t < 3; t++) {
                s16x8 bfr = *(const s16x8*)(wqkv + (t * 256 + 16 * w + il) * 256 + k0 + 8 * gl);
                #pragma unroll
                for (int mi = 0; mi < 4; mi++)
                    acc[mi][t] = __builtin_amdgcn_mfma_f32_16x16x32_bf16(a[mi], bfr, acc[mi][t], 0, 0, 0);
            }
        }
        // V -> VT LDS (region B, transposed)
        {
            float bv = qkv_bias[512 + 16 * w + il];
            #pragma unroll
            for (int mi = 0; mi < 4; mi++) {
                uint2 pk = { cvt2bf(acc[mi][2][0] + bv, acc[mi][2][1] + bv),
                             cvt2bf(acc[mi][2][2] + bv, acc[mi][2][3] + bv) };
                *(uint2*)&lvt[(16 * w + il) * VTS + mi * 16 + gl * 4] = pk;
            }
        }
        __syncthreads();   // (2) x reads done everywhere; region A -> Q|K
        {
            float bq_ = qkv_bias[16 * w + il];
            float bk_ = qkv_bias[256 + 16 * w + il];
            const float QSCL = 0.17677669529663687f * 1.4426950408889634f;  // 1/sqrt(32) * log2(e)
            #pragma unroll
            for (int mi = 0; mi < 4; mi++)
                #pragma unroll
                for (int r = 0; r < 4; r++) {
                    int row = mi * 16 + gl * 4 + r;
                    unsigned u = cvt2bf((acc[mi][0][r] + bq_) * QSCL, acc[mi][1][r] + bk_);
                    lqk[row * LQS + 16 * w + il] = (short)u;
                    lqk[row * LQS + 256 + 16 * w + il] = (short)(u >> 16);
                }
        }
    }
    // issue bias+mask C-init loads early (global, L2/L3-hit; independent of barrier)
    const int cls = ((wy == 7) ? 2 : 0) + ((wx == 7) ? 1 : 0);
    const float* bmp = bm + ((cls * 8 + hh) * 64) * 64;
    f32x4 ci[2][4];
    #pragma unroll
    for (int mi = 0; mi < 2; mi++)
        #pragma unroll
        for (int ni = 0; ni < 4; ni++)
            ci[mi][ni] = *(const f32x4*)&bmp[(ni * 16 + il) * 64 + jh * 32 + mi * 16 + gl * 4];
    __syncthreads();   // (3) Q,K ready

    // ---------------- attention: wave (hh, jh), keys j in [32jh, 32jh+32) ---
    f32x4 s[2][4];
    {
        s16x8 bq[4], ak[2];
        #pragma unroll
        for (int ni = 0; ni < 4; ni++)
            bq[ni] = *(const s16x8*)&lqk[(ni * 16 + il) * LQS + 32 * hh + 8 * gl];
        #pragma unroll
        for (int mi = 0; mi < 2; mi++)
            ak[mi] = *(const s16x8*)&lqk[(jh * 32 + mi * 16 + il) * LQS + 256 + 32 * hh + 8 * gl];
        #pragma unroll
        for (int mi = 0; mi < 2; mi++)
            #pragma unroll
            for (int ni = 0; ni < 4; ni++)
                s[mi][ni] = __builtin_amdgcn_mfma_f32_16x16x32_bf16(ak[mi], bq[ni], ci[mi][ni], 0, 0, 0);
    }
    // s[mi][ni][r] = log2-score[ i = ni*16+il ][ j = 32jh + mi*16 + gl*4 + r ]
    // p = 2^s directly (scores are small; masked = -144, pad = -1e9 -> 0)
    float sm[4] = { 0.f, 0.f, 0.f, 0.f };
    #pragma unroll
    for (int mi = 0; mi < 2; mi++)
        #pragma unroll
        for (int ni = 0; ni < 4; ni++)
            #pragma unroll
            for (int r = 0; r < 4; r++) {
                float p = exp2f(s[mi][ni][r]);
                s[mi][ni][r] = p;
                sm[ni] += p;
            }
    #pragma unroll
    for (int ni = 0; ni < 4; ni++) {
        sm[ni] += __shfl_xor(sm[ni], 16);
        sm[ni] += __shfl_xor(sm[ni], 32);
    }
    if (jh == 0 && gl == 0) {
        #pragma unroll
        for (int ni = 0; ni < 4; ni++) lml[hh * 64 + ni * 16 + il] = sm[ni];
    }
    // pack UNNORMALIZED P (bf16 pairs along j); normalize after cross-half reduce
    unsigned pkd[2][4][2];
    #pragma unroll
    for (int mi = 0; mi < 2; mi++)
        #pragma unroll
        for (int ni = 0; ni < 4; ni++) {
            pkd[mi][ni][0] = cvt2bf(s[mi][ni][0], s[mi][ni][1]);
            pkd[mi][ni][1] = cvt2bf(s[mi][ni][2], s[mi][ni][3]);
        }
    __syncthreads();   // (4) frag reads done -> region A free for lout; lml visible

    // PV: o^T[d][i] += VT[d][j] * P[j][i]
    f32x4 o[2][4];
    {
        s16x8 av[2];
        #pragma unroll
        for (int md = 0; md < 2; md++)
            av[md] = *(const s16x8*)&lvt[(32 * hh + md * 16 + il) * VTS + jh * 32 + 8 * gl];
        #pragma unroll
        for (int ni = 0; ni < 4; ni++) {
            unsigned wd[4];
            #pragma unroll
            for (int q = 0; q < 4; q++) {
                int src = (2 * (gl & 1) + (q >> 1)) * 16 + il;
                unsigned v0 = (unsigned)__shfl((int)pkd[0][ni][q & 1], src);
                unsigned v1 = (unsigned)__shfl((int)pkd[1][ni][q & 1], src);
                wd[q] = (gl & 2) ? v1 : v0;
            }
            union { unsigned u[4]; s16x8 v; } cv;
            cv.u[0] = wd[0]; cv.u[1] = wd[1]; cv.u[2] = wd[2]; cv.u[3] = wd[3];
            #pragma unroll
            for (int md = 0; md < 2; md++)
                o[md][ni] = __builtin_amdgcn_mfma_f32_16x16x32_bf16(av[md], cv.v, (f32x4){0.f,0.f,0.f,0.f}, 0, 0, 0);
        }
    }
    // cross-pair reduce: jh0 writes raw f32; jh1 adds, normalizes, emits bf16 la
    if (jh == 0) {
        #pragma unroll
        for (int md = 0; md < 2; md++)
            #pragma unroll
            for (int ni = 0; ni < 4; ni++)
                *(f32x4*)&lout[(ni * 16 + il) * FOS + 32 * hh + md * 16 + gl * 4] = o[md][ni];
    }
    __syncthreads();   // (5)
    if (jh == 1) {
        float sc[4];
        #pragma unroll
        for (int ni = 0; ni < 4; ni++)
            sc[ni] = __builtin_amdgcn_rcpf(lml[hh * 64 + ni * 16 + il] + sm[ni]);
        #pragma unroll
        for (int md = 0; md < 2; md++)
            #pragma unroll
            for (int ni = 0; ni < 4; ni++) {
                f32x4 t = *(const f32x4*)&lout[(ni * 16 + il) * FOS + 32 * hh + md * 16 + gl * 4];
                float a0 = (t.x + o[md][ni][0]) * sc[ni];
                float a1 = (t.y + o[md][ni][1]) * sc[ni];
                float a2 = (t.z + o[md][ni][2]) * sc[ni];
                float a3 = (t.w + o[md][ni][3]) * sc[ni];
                uint2 pk = { cvt2bf(a0, a1), cvt2bf(a2, a3) };
                *(uint2*)&la[(ni * 16 + il) * LAS + 32 * hh + md * 16 + gl * 4] = pk;
            }
    }
    __syncthreads();   // (6) la ready, lout dead

    // ---------------- proj GEMM: wave w -> out cols [16w,16w+16) ------------
    {
        f32x4 acc[4];
        #pragma unroll
        for (int mi = 0; mi < 4; mi++) acc[mi] = (f32x4){0.f, 0.f, 0.f, 0.f};
        for (int k0 = 0; k0 < 256; k0 += 32) {
            s16x8 bw = *(const s16x8*)(wproj + (16 * w + il) * 256 + k0 + 8 * gl);
            #pragma unroll
            for (int mi = 0; mi < 4; mi++) {
                s16x8 a = *(const s16x8*)&la[(mi * 16 + il) * LAS + k0 + 8 * gl];
                acc[mi] = __builtin_amdgcn_mfma_f32_16x16x32_bf16(a, bw, acc[mi], 0, 0, 0);
            }
        }
        float pb = proj_bias[16 * w + il];
        float* fout = lout;
        #pragma unroll
        for (int mi = 0; mi < 4; mi++)
            #pragma unroll
            for (int r = 0; r < 4; r++) {
                int t = mi * 16 + gl * 4 + r;
                if (t < 49) fout[t * FOS + 16 * w + il] = acc[mi][r] + pb;
            }
    }
    __syncthreads();   // (7)
    // coalesced store with reverse roll: full 1KB token rows
    for (int i = tid; i < 3136; i += 1024) {   // 49 rows x 64 float4 chunks
        int t = i >> 6, c4 = (i & 63) << 2;
        f32x4 v = *(const f32x4*)&lout[t * FOS + c4];
        int ty = t / 7, tx = t % 7;
        int R = wy * 7 + ty + 3; if (R >= 56) R -= 56;
        int C = wx * 7 + tx + 3; if (C >= 56) C -= 56;
        *(f32x4*)(out + (((b * 56 + R) * 56 + C) << 8) + c4) = v;
    }
}

extern "C" void kernel_launch(void* const* d_in, const int* in_sizes, int n_in,
                              void* d_out, int out_size, void* d_ws, size_t ws_size,
                              hipStream_t stream) {
    const float* x   = (const float*)d_in[0];
    const float* qw  = (const float*)d_in[1];
    const float* qb  = (const float*)d_in[2];
    const float* pw  = (const float*)d_in[3];
    const float* pb  = (const float*)d_in[4];
    const float* rpb = (const float*)d_in[5];

    short* wqkv  = (short*)d_ws;                       // 768*256 bf16 = 393216 B
    short* wproj = wqkv + 768 * 256;                   // 256*256 bf16 = 131072 B
    float* bmt   = (float*)((char*)d_ws + 524288);     // 4*8*64*64 f32 = 524288 B

    wcvt_kernel<<<128, 256, 0, stream>>>(qw, pw, wqkv, wproj);
    bmgen_kernel<<<512, 256, 0, stream>>>(rpb, bmt);
    swin_kernel<<<2048, 1024, 0, stream>>>(x, qb, pb, wqkv, wproj, bmt, (float*)d_out);
}